// Round 12
// baseline (328.381 us; speedup 1.0000x reference)
//
#include <hip/hip_runtime.h>
#include <stdint.h>

#define M_ 8192   // B*L
#define D_ 768
#define N_ 8192

typedef unsigned short u16;
typedef __attribute__((ext_vector_type(8))) unsigned short us8;
typedef __attribute__((ext_vector_type(8))) __bf16 bf16x8;
typedef __attribute__((ext_vector_type(4))) float f32x4;

__device__ __forceinline__ u16 f2bf(float f) {
  uint32_t u = __builtin_bit_cast(uint32_t, f);
  u += 0x7FFFu + ((u >> 16) & 1u);   // RNE
  return (u16)(u >> 16);
}
__device__ __forceinline__ float bf2f(u16 u) {
  return __builtin_bit_cast(float, ((uint32_t)u) << 16);
}

__device__ __forceinline__ void gload_lds16(const void* g, void* l) {
  __builtin_amdgcn_global_load_lds(
      (__attribute__((address_space(1))) void*)g,
      (__attribute__((address_space(3))) void*)l, 16, 0, 0);
}

// ---------------- f32 -> bf16 convert (vectorized) ----------------
__global__ __launch_bounds__(256)
void k_cvt_bf16(const float* __restrict__ in, u16* __restrict__ out, int n4) {
  int stride = gridDim.x * blockDim.x;
  for (int i = blockIdx.x * blockDim.x + threadIdx.x; i < n4; i += stride) {
    float4 v = reinterpret_cast<const float4*>(in)[i];
    ushort4 o;
    o.x = f2bf(v.x); o.y = f2bf(v.y); o.z = f2bf(v.z); o.w = f2bf(v.w);
    reinterpret_cast<ushort4*>(out)[i] = o;
  }
}

// ---------------- Vt[d][n] = bf16(prior[n] * dic[n][d]) ----------------
__global__ __launch_bounds__(256)
void k_build_vt(const float* __restrict__ dic, const float* __restrict__ prior,
                u16* __restrict__ Vt) {
  __shared__ float t[32][33];
  const int n0 = blockIdx.x * 32, d0 = blockIdx.y * 32;
  const int tx = threadIdx.x, ty = threadIdx.y;
  #pragma unroll
  for (int i = ty; i < 32; i += 8)
    t[i][tx] = dic[(size_t)(n0 + i) * D_ + d0 + tx] * prior[n0 + i];
  __syncthreads();
  #pragma unroll
  for (int i = ty; i < 32; i += 8)
    Vt[(size_t)(d0 + i) * N_ + n0 + tx] = f2bf(t[tx][i]);
}

// ============ 256x256 NT bf16 GEMM — round-7 schedule (best measured) ======
// EP 0 (S path): Cb = bf16(exp(acc*scale)) — softmax without max-subtraction
//   (validated rounds 10/11). Row-sums via LDS scratch reduce -> one
//   atomicAdd per row per block into Cf[row].
template<int EP>
__global__ __launch_bounds__(512, 2)
void k_gemm8(const u16* __restrict__ A, const u16* __restrict__ Bm,
             u16* __restrict__ Cb, float* __restrict__ Cf, float scale,
             long ldk, int K, int Ncols, int nbx, int tps, long partStride) {
  extern __shared__ u16 ldsu[];   // 65536 u16 = 128 KiB: [buf2][mat2][16384]
  const int tid = threadIdx.x;
  const int lane = tid & 63, wid = tid >> 6;
  const int wr = wid >> 2, wc = wid & 3;
  const int L15 = lane & 15, L7 = lane & 7, g = lane >> 4;

  // T1: XCD swizzle, only when bijective (grid multiple of 8)
  const int nwg = gridDim.x;
  const int bid = blockIdx.x;
  const int wg = ((nwg & 7) == 0) ? ((bid & 7) * (nwg >> 3) + (bid >> 3)) : bid;
  const int s = wg / tps;          // split index
  const int r = wg % tps;
  const int bx = r % nbx, by = r / nbx;
  const long m0 = (long)by * 256;
  const long n0 = (long)bx * 256;
  const int NT = K >> 6;

  // ds-read bases (u16 units, excl. buf term). T2 swizzle: slot ^= row&7.
  int aBase[2], bBase[2];
  #pragma unroll
  for (int ks = 0; ks < 2; ++ks) {
    const int slot = (((ks * 4 + g) ^ L7) << 3);
    aBase[ks] = wr * 8192 + L15 * 64 + slot;
    bBase[ks] = 16384 + (wc >> 1) * 8192 + (wc & 1) * 4096 + L15 * 64 + slot;
  }

  // stage addressing: linear LDS dest, inverse-swizzled global source
  const int rowoff = wid * 8 + (lane >> 3);
  const int colsw = ((lane & 7) ^ (lane >> 3)) << 3;   // u16
  const u16* Ag = A + m0 * ldk + (long)s * K;
  const u16* Bg = Bm + n0 * ldk + (long)s * K;
  u16* ldsW = ldsu + tid * 8;

  // one 64-row gload: tile t, matrix mat, base row r0 in {0,64,128,192}
  auto g1 = [&](int t, int mat, int r0) {
    if (t >= NT) return;
    const u16* src = (mat ? Bg : Ag) + (size_t)(r0 + rowoff) * ldk
                     + (size_t)t * 64 + colsw;
    gload_lds16(src, ldsW + (t & 1) * 32768 + mat * 16384 + (r0 >> 6) * 512 * 8);
  };

#define RD_B()                                                              \
  _Pragma("unroll") for (int j = 0; j < 4; ++j)                             \
    _Pragma("unroll") for (int ks = 0; ks < 2; ++ks)                        \
      bfr[j][ks] = __builtin_bit_cast(bf16x8,                               \
          *reinterpret_cast<const us8*>(&ldsu[bufOff + bBase[ks] + j * 1024]));
#define RD_A(q)                                                             \
  _Pragma("unroll") for (int t = 0; t < 2; ++t)                             \
    _Pragma("unroll") for (int ks = 0; ks < 2; ++ks)                        \
      afr[t][ks] = __builtin_bit_cast(bf16x8,                               \
          *reinterpret_cast<const us8*>(                                    \
              &ldsu[bufOff + aBase[ks] + (2 * (q) + t) * 1024]));
#define LGKM0()                                                             \
  asm volatile("s_waitcnt lgkmcnt(0)" ::: "memory");                        \
  __builtin_amdgcn_sched_barrier(0);
#define MM(p)                                                               \
  __builtin_amdgcn_s_setprio(1);                                            \
  _Pragma("unroll") for (int t = 0; t < 2; ++t)                             \
    _Pragma("unroll") for (int j = 0; j < 4; ++j)                           \
      _Pragma("unroll") for (int ks = 0; ks < 2; ++ks)                      \
        acc[2 * (p) + t][j] = __builtin_amdgcn_mfma_f32_16x16x32_bf16(      \
            afr[t][ks], bfr[j][ks], acc[2 * (p) + t][j], 0, 0, 0);          \
  __builtin_amdgcn_s_setprio(0);

  // prologue: tile0 full (8) + tile1 {B-h0,B-h1,A-lo} (6); tile0 resident
  g1(0, 1, 0); g1(0, 1, 64); g1(0, 1, 128); g1(0, 1, 192);
  g1(0, 0, 0); g1(0, 0, 128); g1(0, 0, 64); g1(0, 0, 192);
  g1(1, 1, 0); g1(1, 1, 64);
  g1(1, 1, 128); g1(1, 1, 192);
  g1(1, 0, 0); g1(1, 0, 128);
  asm volatile("s_waitcnt vmcnt(6)" ::: "memory");
  __builtin_amdgcn_s_barrier();

  f32x4 acc[8][4] = {};

  for (int k = 0; k < NT; ++k) {
    const int bufOff = (k & 1) * 32768;
    bf16x8 bfr[4][2];

    { // ---- ph0: reads B(8)+A-quad0(4) ; stage A-hi(k+1) ----
      bf16x8 afr[2][2];
      g1(k + 1, 0, 64); g1(k + 1, 0, 192);
      RD_B(); RD_A(0);
      asm volatile("s_waitcnt lgkmcnt(8)" ::: "memory");  // pacing
      __builtin_amdgcn_s_barrier();
      LGKM0();
      MM(0);
    }
    { // ---- ph1: reads A-quad1 ; stage B-h0(k+2) ----
      bf16x8 afr[2][2];
      RD_A(1);
      g1(k + 2, 1, 0); g1(k + 2, 1, 64);
      __builtin_amdgcn_s_barrier();
      LGKM0();
      MM(1);
    }
    { // ---- ph2: reads A-quad2 ; stage B-h1(k+2) ----
      bf16x8 afr[2][2];
      RD_A(2);
      g1(k + 2, 1, 128); g1(k + 2, 1, 192);
      __builtin_amdgcn_s_barrier();
      LGKM0();
      MM(2);
    }
    { // ---- ph3: reads A-quad3 ; stage A-lo(k+2) ; counted vmcnt ----
      bf16x8 afr[2][2];
      RD_A(3);
      g1(k + 2, 0, 0); g1(k + 2, 0, 128);
      if (k < NT - 2) asm volatile("s_waitcnt vmcnt(6)" ::: "memory");
      else            asm volatile("s_waitcnt vmcnt(0)" ::: "memory");
      __builtin_amdgcn_s_barrier();
      LGKM0();
      MM(3);
    }
  }
#undef RD_B
#undef RD_A
#undef LGKM0
#undef MM

  // epilogue: C/D layout col=lane&15, row=(lane>>4)*4+q
  if (EP == 0) {
    // P~ = exp(acc*scale); row-sums via LDS scratch (LDS free after K-loop)
    __builtin_amdgcn_s_barrier();          // all waves done with LDS tiles
    float* lsum = reinterpret_cast<float*>(ldsu);   // [256][68] f32, padded
    #pragma unroll
    for (int i = 0; i < 8; ++i) {
      #pragma unroll
      for (int q = 0; q < 4; ++q) {
        const int rl = wr * 128 + i * 16 + g * 4 + q;
        const long row = m0 + rl;
        float rsum = 0.f;
        #pragma unroll
        for (int j = 0; j < 4; ++j) {
          float v = __expf(acc[i][j][q] * scale);
          rsum += v;
          Cb[row * (long)Ncols + n0 + wc * 64 + j * 16 + L15] = f2bf(v);
        }
        lsum[rl * 68 + wc * 16 + L15] = rsum;   // 64 partials per row
      }
    }
    __builtin_amdgcn_s_barrier();
    {
      const int rl = tid >> 1, half = tid & 1;    // 2 threads per row
      const float4* rp =
          reinterpret_cast<const float4*>(&lsum[rl * 68 + half * 32]);
      float s4 = 0.f;
      #pragma unroll
      for (int c = 0; c < 8; ++c) {
        float4 v = rp[c];
        s4 += (v.x + v.y) + (v.z + v.w);
      }
      s4 += __shfl_xor(s4, 1);
      if (half == 0) atomicAdd(&Cf[m0 + rl], s4);  // 256 atomics per block
    }
  } else {
    #pragma unroll
    for (int i = 0; i < 8; ++i)
      #pragma unroll
      for (int j = 0; j < 4; ++j)
        #pragma unroll
        for (int q = 0; q < 4; ++q) {
          long row = m0 + wr * 128 + i * 16 + g * 4 + q;
          long col = n0 + wc * 64 + j * 16 + L15;
          Cf[(long)s * partStride + row * (long)Ncols + col] = acc[i][j][q];
        }
  }
}

// ---------- 128x128 NT bf16 GEMM, T2-swizzled (projections + PV) ----------
// EP 1: bf16 out = acc + bias[col]
// EP 3: f32  out = acc / rowsum[row]   (PV epilogue; one writer per cell)
template<int EP>
__global__ __launch_bounds__(256, 2)
void k_gemm_nt(const u16* __restrict__ A, const u16* __restrict__ Bm,
               float* __restrict__ Cf, u16* __restrict__ Cb,
               const float* __restrict__ bias, const float* __restrict__ rowsum,
               float scale, int N, long K) {
  __shared__ u16 Al[128 * 64];
  __shared__ u16 Bl[128 * 64];
  const int tid = threadIdx.x;
  const int lane = tid & 63;
  const int wave = tid >> 6;
  const int wr = wave >> 1, wc = wave & 1;
  const int L15 = lane & 15, L7 = lane & 7, g = lane >> 4;
  const long m0 = (long)blockIdx.y * 128;
  const long n0 = (long)blockIdx.x * 128;

  f32x4 acc[4][4] = {};

  // T2 swizzle (same involution as k_gemm8): LDS slot' = slot ^ (row&7);
  // linear LDS dest, inverse-swizzled global source column chunk.
  const int colsw = ((tid & 7) ^ ((tid >> 3) & 7)) * 8;   // u16
  const u16* gA = A + (m0 + (tid >> 3)) * K + colsw;
  const u16* gB = Bm + (n0 + (tid >> 3)) * K + colsw;
  const int aslot = ((g) ^ L7) * 8;        // ks=0 slot; ks=1 adds 4*8 XORed
  // read offsets for ks=0/1 computed per use below

  for (long kt = 0; kt < K; kt += 64) {
    __syncthreads();
    #pragma unroll
    for (int r = 0; r < 4; ++r) {
      gload_lds16(gA + (size_t)(r * 32) * K + kt, &Al[r * 2048 + tid * 8]);
      gload_lds16(gB + (size_t)(r * 32) * K + kt, &Bl[r * 2048 + tid * 8]);
    }
    __syncthreads();
    #pragma unroll
    for (int ks = 0; ks < 2; ++ks) {
      const int slot = ((ks * 4 + g) ^ L7) * 8;
      bf16x8 av[4], bv[4];
      #pragma unroll
      for (int i = 0; i < 4; ++i) {
        av[i] = __builtin_bit_cast(bf16x8, *reinterpret_cast<const us8*>(
            &Al[(wr * 64 + i * 16 + L15) * 64 + slot]));
        bv[i] = __builtin_bit_cast(bf16x8, *reinterpret_cast<const us8*>(
            &Bl[(wc * 64 + i * 16 + L15) * 64 + slot]));
      }
      #pragma unroll
      for (int i = 0; i < 4; ++i)
        #pragma unroll
        for (int j = 0; j < 4; ++j)
          acc[i][j] = __builtin_amdgcn_mfma_f32_16x16x32_bf16(av[i], bv[j], acc[i][j], 0, 0, 0);
    }
  }
  (void)aslot;

  #pragma unroll
  for (int i = 0; i < 4; ++i) {
    #pragma unroll
    for (int q = 0; q < 4; ++q) {
      long row = m0 + wr * 64 + i * 16 + g * 4 + q;
      float inv;
      if (EP == 3) inv = 1.0f / rowsum[row];
      #pragma unroll
      for (int j = 0; j < 4; ++j) {
        long col = n0 + wc * 64 + j * 16 + L15;
        float v = acc[i][j][q];
        if (EP == 1) Cb[row * N + col] = f2bf(v + bias[col]);
        else         Cf[row * N + col] = v * inv;
      }
    }
  }
  (void)scale;
}

extern "C" void kernel_launch(void* const* d_in, const int* in_sizes, int n_in,
                              void* d_out, int out_size, void* d_ws, size_t ws_size,
                              hipStream_t stream) {
  (void)in_sizes; (void)n_in; (void)out_size;
  const float* y     = (const float*)d_in[0];
  const float* Wy_w  = (const float*)d_in[1];
  const float* Wy_b  = (const float*)d_in[2];
  const float* Wz_w  = (const float*)d_in[3];
  const float* Wz_b  = (const float*)d_in[4];
  const float* dic   = (const float*)d_in[5];
  const float* prior = (const float*)d_in[6];
  float* out = (float*)d_out;

  // allow 128 KiB dynamic LDS (unconditional, idempotent, capture-safe)
  hipFuncSetAttribute(reinterpret_cast<const void*>(&k_gemm8<0>),
                      hipFuncAttributeMaxDynamicSharedMemorySize, 131072);

  char* base = (char*)d_ws;
  size_t off = 0;
  auto alloc = [&](size_t bytes) -> char* {
    char* p = base + off;
    off = (off + bytes + 255) & ~(size_t)255;
    return p;
  };
  u16*  Yb   = (u16*)alloc((size_t)M_ * D_ * 2);
  u16*  Db   = (u16*)alloc((size_t)N_ * D_ * 2);
  u16*  Wyb  = (u16*)alloc((size_t)D_ * D_ * 2);
  u16*  Wzb  = (u16*)alloc((size_t)D_ * D_ * 2);
  u16*  Qb   = (u16*)alloc((size_t)M_ * D_ * 2);
  u16*  Kb   = (u16*)alloc((size_t)N_ * D_ * 2);
  u16*  Vt   = (u16*)alloc((size_t)D_ * N_ * 2);
  float* rowsum = (float*)alloc((size_t)M_ * 4);
  size_t fixed = off;
  // chunk M so S-chunk (bf16) fits in ws
  int Mc = M_;
  while (Mc > 256 && fixed + (size_t)Mc * N_ * 2 > ws_size) Mc >>= 1;
  u16* Sc = (u16*)alloc((size_t)Mc * N_ * 2);

  // zero row-sum accumulators (stream-ordered, capture-safe)
  hipMemsetAsync(rowsum, 0, (size_t)M_ * 4, stream);

  auto cvt = [&](const float* src, u16* dst, size_t n) {
    int n4 = (int)(n / 4);
    int blocks = (n4 + 255) / 256;
    if (blocks > 2048) blocks = 2048;
    hipLaunchKernelGGL(k_cvt_bf16, dim3(blocks), dim3(256), 0, stream, src, dst, n4);
  };
  cvt(y,    Yb,  (size_t)M_ * D_);
  cvt(dic,  Db,  (size_t)N_ * D_);
  cvt(Wy_w, Wyb, (size_t)D_ * D_);
  cvt(Wz_w, Wzb, (size_t)D_ * D_);

  hipLaunchKernelGGL(k_build_vt, dim3(N_ / 32, D_ / 32), dim3(32, 8), 0, stream,
                     dic, prior, Vt);

  // Q = Yb * Wyb^T + by ; K = Db * Wzb^T + bz   (bf16 out, swizzled kernel)
  hipLaunchKernelGGL(HIP_KERNEL_NAME(k_gemm_nt<1>), dim3(D_ / 128, M_ / 128), dim3(256), 0, stream,
                     Yb, Wyb, (float*)nullptr, Qb, Wy_b, (const float*)nullptr, 0.f, D_, (long)D_);
  hipLaunchKernelGGL(HIP_KERNEL_NAME(k_gemm_nt<1>), dim3(D_ / 128, N_ / 128), dim3(256), 0, stream,
                     Db, Wzb, (float*)nullptr, Kb, Wz_b, (const float*)nullptr, 0.f, D_, (long)D_);

  const float scale = 0.036084391824351615f;  // 1/sqrt(768)
  for (int mc = 0; mc < M_; mc += Mc) {
    // P~ = exp(Q*K^T * scale) (bf16) + row-sums, fused into the S GEMM
    {
      const int nbx = N_ / 256, nby = Mc / 256;
      hipLaunchKernelGGL(HIP_KERNEL_NAME(k_gemm8<0>), dim3(nbx * nby), dim3(512), 131072, stream,
                         Qb + (size_t)mc * D_, Kb, Sc, rowsum + mc, scale,
                         (long)D_, D_, N_, nbx, nbx * nby, 0L);
    }
    // out = (P~ * Vt^T) / rowsum — swizzled 128^2 kernel, full fill (6 x Mc/128)
    hipLaunchKernelGGL(HIP_KERNEL_NAME(k_gemm_nt<3>), dim3(D_ / 128, Mc / 128), dim3(256), 0, stream,
                       Sc, Vt, out + (size_t)mc * D_, (u16*)nullptr,
                       (const float*)nullptr, rowsum + mc, 0.f, D_, (long)N_);
  }
}

// Round 13
// 298.168 us; speedup vs baseline: 1.1013x; 1.1013x over previous
//
#include <hip/hip_runtime.h>
#include <stdint.h>

#define M_ 8192   // B*L
#define D_ 768
#define N_ 8192

typedef unsigned short u16;
typedef __attribute__((ext_vector_type(8))) unsigned short us8;
typedef __attribute__((ext_vector_type(8))) __bf16 bf16x8;
typedef __attribute__((ext_vector_type(4))) float f32x4;

__device__ __forceinline__ u16 f2bf(float f) {
  uint32_t u = __builtin_bit_cast(uint32_t, f);
  u += 0x7FFFu + ((u >> 16) & 1u);   // RNE
  return (u16)(u >> 16);
}
__device__ __forceinline__ float bf2f(u16 u) {
  return __builtin_bit_cast(float, ((uint32_t)u) << 16);
}

__device__ __forceinline__ void gload_lds16(const void* g, void* l) {
  __builtin_amdgcn_global_load_lds(
      (__attribute__((address_space(1))) void*)g,
      (__attribute__((address_space(3))) void*)l, 16, 0, 0);
}

// ---------------- f32 -> bf16 convert (vectorized) ----------------
__global__ __launch_bounds__(256)
void k_cvt_bf16(const float* __restrict__ in, u16* __restrict__ out, int n4) {
  int stride = gridDim.x * blockDim.x;
  for (int i = blockIdx.x * blockDim.x + threadIdx.x; i < n4; i += stride) {
    float4 v = reinterpret_cast<const float4*>(in)[i];
    ushort4 o;
    o.x = f2bf(v.x); o.y = f2bf(v.y); o.z = f2bf(v.z); o.w = f2bf(v.w);
    reinterpret_cast<ushort4*>(out)[i] = o;
  }
}

// ---- fused: Db[n][d] = bf16(dic[n][d]);  Vt[d][n] = bf16(prior[n]*dic[n][d])
__global__ __launch_bounds__(256)
void k_build_vt(const float* __restrict__ dic, const float* __restrict__ prior,
                u16* __restrict__ Db, u16* __restrict__ Vt) {
  __shared__ float t[32][33];
  const int n0 = blockIdx.x * 32, d0 = blockIdx.y * 32;
  const int tx = threadIdx.x, ty = threadIdx.y;
  #pragma unroll
  for (int i = ty; i < 32; i += 8) {
    float v = dic[(size_t)(n0 + i) * D_ + d0 + tx];
    Db[(size_t)(n0 + i) * D_ + d0 + tx] = f2bf(v);
    t[i][tx] = v * prior[n0 + i];
  }
  __syncthreads();
  #pragma unroll
  for (int i = ty; i < 32; i += 8)
    Vt[(size_t)(d0 + i) * N_ + n0 + tx] = f2bf(t[tx][i]);
}

// ============ 256x256 NT bf16 GEMM — round-7 schedule (best measured) ======
// EP 0 (S path): Cb = bf16(exp(acc*scale)) — softmax without max-subtraction
//   (validated rounds 10-12). Row-sums via LDS scratch reduce -> one
//   atomicAdd per row per block into Cf[row].
// EP 1 (PV path): f32 Cf[s*partStride + row*Ncols + col] = acc (split-K).
template<int EP>
__global__ __launch_bounds__(512, 2)
void k_gemm8(const u16* __restrict__ A, const u16* __restrict__ Bm,
             u16* __restrict__ Cb, float* __restrict__ Cf, float scale,
             long ldk, int K, int Ncols, int nbx, int tps, long partStride) {
  extern __shared__ u16 ldsu[];   // 65536 u16 = 128 KiB: [buf2][mat2][16384]
  const int tid = threadIdx.x;
  const int lane = tid & 63, wid = tid >> 6;
  const int wr = wid >> 2, wc = wid & 3;
  const int L15 = lane & 15, L7 = lane & 7, g = lane >> 4;

  // T1: XCD swizzle, only when bijective (grid multiple of 8)
  const int nwg = gridDim.x;
  const int bid = blockIdx.x;
  const int wg = ((nwg & 7) == 0) ? ((bid & 7) * (nwg >> 3) + (bid >> 3)) : bid;
  const int s = wg / tps;          // split index
  const int r = wg % tps;
  const int bx = r % nbx, by = r / nbx;
  const long m0 = (long)by * 256;
  const long n0 = (long)bx * 256;
  const int NT = K >> 6;

  // ds-read bases (u16 units, excl. buf term). T2 swizzle: slot ^= row&7.
  int aBase[2], bBase[2];
  #pragma unroll
  for (int ks = 0; ks < 2; ++ks) {
    const int slot = (((ks * 4 + g) ^ L7) << 3);
    aBase[ks] = wr * 8192 + L15 * 64 + slot;
    bBase[ks] = 16384 + (wc >> 1) * 8192 + (wc & 1) * 4096 + L15 * 64 + slot;
  }

  // stage addressing: linear LDS dest, inverse-swizzled global source
  const int rowoff = wid * 8 + (lane >> 3);
  const int colsw = ((lane & 7) ^ (lane >> 3)) << 3;   // u16
  const u16* Ag = A + m0 * ldk + (long)s * K;
  const u16* Bg = Bm + n0 * ldk + (long)s * K;
  u16* ldsW = ldsu + tid * 8;

  // one 64-row gload: tile t, matrix mat, base row r0 in {0,64,128,192}
  auto g1 = [&](int t, int mat, int r0) {
    if (t >= NT) return;
    const u16* src = (mat ? Bg : Ag) + (size_t)(r0 + rowoff) * ldk
                     + (size_t)t * 64 + colsw;
    gload_lds16(src, ldsW + (t & 1) * 32768 + mat * 16384 + (r0 >> 6) * 512 * 8);
  };

#define RD_B()                                                              \
  _Pragma("unroll") for (int j = 0; j < 4; ++j)                             \
    _Pragma("unroll") for (int ks = 0; ks < 2; ++ks)                        \
      bfr[j][ks] = __builtin_bit_cast(bf16x8,                               \
          *reinterpret_cast<const us8*>(&ldsu[bufOff + bBase[ks] + j * 1024]));
#define RD_A(q)                                                             \
  _Pragma("unroll") for (int t = 0; t < 2; ++t)                             \
    _Pragma("unroll") for (int ks = 0; ks < 2; ++ks)                        \
      afr[t][ks] = __builtin_bit_cast(bf16x8,                               \
          *reinterpret_cast<const us8*>(                                    \
              &ldsu[bufOff + aBase[ks] + (2 * (q) + t) * 1024]));
#define LGKM0()                                                             \
  asm volatile("s_waitcnt lgkmcnt(0)" ::: "memory");                        \
  __builtin_amdgcn_sched_barrier(0);
#define MM(p)                                                               \
  __builtin_amdgcn_s_setprio(1);                                            \
  _Pragma("unroll") for (int t = 0; t < 2; ++t)                             \
    _Pragma("unroll") for (int j = 0; j < 4; ++j)                           \
      _Pragma("unroll") for (int ks = 0; ks < 2; ++ks)                      \
        acc[2 * (p) + t][j] = __builtin_amdgcn_mfma_f32_16x16x32_bf16(      \
            afr[t][ks], bfr[j][ks], acc[2 * (p) + t][j], 0, 0, 0);          \
  __builtin_amdgcn_s_setprio(0);

  // prologue: tile0 full (8) + tile1 {B-h0,B-h1,A-lo} (6); tile0 resident
  g1(0, 1, 0); g1(0, 1, 64); g1(0, 1, 128); g1(0, 1, 192);
  g1(0, 0, 0); g1(0, 0, 128); g1(0, 0, 64); g1(0, 0, 192);
  g1(1, 1, 0); g1(1, 1, 64);
  g1(1, 1, 128); g1(1, 1, 192);
  g1(1, 0, 0); g1(1, 0, 128);
  asm volatile("s_waitcnt vmcnt(6)" ::: "memory");
  __builtin_amdgcn_s_barrier();

  f32x4 acc[8][4] = {};

  for (int k = 0; k < NT; ++k) {
    const int bufOff = (k & 1) * 32768;
    bf16x8 bfr[4][2];

    { // ---- ph0: reads B(8)+A-quad0(4) ; stage A-hi(k+1) ----
      bf16x8 afr[2][2];
      g1(k + 1, 0, 64); g1(k + 1, 0, 192);
      RD_B(); RD_A(0);
      asm volatile("s_waitcnt lgkmcnt(8)" ::: "memory");  // pacing
      __builtin_amdgcn_s_barrier();
      LGKM0();
      MM(0);
    }
    { // ---- ph1: reads A-quad1 ; stage B-h0(k+2) ----
      bf16x8 afr[2][2];
      RD_A(1);
      g1(k + 2, 1, 0); g1(k + 2, 1, 64);
      __builtin_amdgcn_s_barrier();
      LGKM0();
      MM(1);
    }
    { // ---- ph2: reads A-quad2 ; stage B-h1(k+2) ----
      bf16x8 afr[2][2];
      RD_A(2);
      g1(k + 2, 1, 128); g1(k + 2, 1, 192);
      __builtin_amdgcn_s_barrier();
      LGKM0();
      MM(2);
    }
    { // ---- ph3: reads A-quad3 ; stage A-lo(k+2) ; counted vmcnt ----
      bf16x8 afr[2][2];
      RD_A(3);
      g1(k + 2, 0, 0); g1(k + 2, 0, 128);
      if (k < NT - 2) asm volatile("s_waitcnt vmcnt(6)" ::: "memory");
      else            asm volatile("s_waitcnt vmcnt(0)" ::: "memory");
      __builtin_amdgcn_s_barrier();
      LGKM0();
      MM(3);
    }
  }
#undef RD_B
#undef RD_A
#undef LGKM0
#undef MM

  // epilogue: C/D layout col=lane&15, row=(lane>>4)*4+q
  if (EP == 0) {
    // P~ = exp(acc*scale); row-sums via LDS scratch (LDS free after K-loop)
    __builtin_amdgcn_s_barrier();          // all waves done with LDS tiles
    float* lsum = reinterpret_cast<float*>(ldsu);   // [256][68] f32, padded
    #pragma unroll
    for (int i = 0; i < 8; ++i) {
      #pragma unroll
      for (int q = 0; q < 4; ++q) {
        const int rl = wr * 128 + i * 16 + g * 4 + q;
        const long row = m0 + rl;
        float rsum = 0.f;
        #pragma unroll
        for (int j = 0; j < 4; ++j) {
          float v = __expf(acc[i][j][q] * scale);
          rsum += v;
          Cb[row * (long)Ncols + n0 + wc * 64 + j * 16 + L15] = f2bf(v);
        }
        lsum[rl * 68 + wc * 16 + L15] = rsum;   // 64 partials per row
      }
    }
    __builtin_amdgcn_s_barrier();
    {
      const int rl = tid >> 1, half = tid & 1;    // 2 threads per row
      const float4* rp =
          reinterpret_cast<const float4*>(&lsum[rl * 68 + half * 32]);
      float s4 = 0.f;
      #pragma unroll
      for (int c = 0; c < 8; ++c) {
        float4 v = rp[c];
        s4 += (v.x + v.y) + (v.z + v.w);
      }
      s4 += __shfl_xor(s4, 1);
      if (half == 0) atomicAdd(&Cf[m0 + rl], s4);  // 256 atomics per block
    }
  } else {
    #pragma unroll
    for (int i = 0; i < 8; ++i)
      #pragma unroll
      for (int j = 0; j < 4; ++j)
        #pragma unroll
        for (int q = 0; q < 4; ++q) {
          long row = m0 + wr * 128 + i * 16 + g * 4 + q;
          long col = n0 + wc * 64 + j * 16 + L15;
          Cf[(long)s * partStride + row * (long)Ncols + col] = acc[i][j][q];
        }
  }
}

// -------- out = (part0 + part1) / rowsum[row], vectorized --------
__global__ __launch_bounds__(256)
void k_reduce2(const float* __restrict__ part, long partStride,
               const float* __restrict__ rowsum, float* __restrict__ out, int n4) {
  int stride = gridDim.x * blockDim.x;
  const float4* p0 = reinterpret_cast<const float4*>(part);
  const float4* p1 = reinterpret_cast<const float4*>(part + partStride);
  for (int i = blockIdx.x * blockDim.x + threadIdx.x; i < n4; i += stride) {
    float4 a = p0[i], b = p1[i];
    float sc = 1.0f / rowsum[(i * 4) / D_];  // D_%4==0: all 4 elems same row
    float4 o;
    o.x = (a.x + b.x) * sc; o.y = (a.y + b.y) * sc;
    o.z = (a.z + b.z) * sc; o.w = (a.w + b.w) * sc;
    reinterpret_cast<float4*>(out)[i] = o;
  }
}

// ---------- 128x128 NT bf16 GEMM, T2-swizzled (projections) ----------
// EP 1: bf16 out = acc + bias[col]   (conflicts=0 verified round 12)
template<int EP>
__global__ __launch_bounds__(256, 2)
void k_gemm_nt(const u16* __restrict__ A, const u16* __restrict__ Bm,
               float* __restrict__ Cf, u16* __restrict__ Cb,
               const float* __restrict__ bias, const float* __restrict__ rowsum,
               float scale, int N, long K) {
  __shared__ u16 Al[128 * 64];
  __shared__ u16 Bl[128 * 64];
  const int tid = threadIdx.x;
  const int lane = tid & 63;
  const int wave = tid >> 6;
  const int wr = wave >> 1, wc = wave & 1;
  const int L15 = lane & 15, L7 = lane & 7, g = lane >> 4;
  const long m0 = (long)blockIdx.y * 128;
  const long n0 = (long)blockIdx.x * 128;

  f32x4 acc[4][4] = {};

  // T2 swizzle: linear LDS dest, inverse-swizzled global source column chunk.
  const int colsw = ((tid & 7) ^ ((tid >> 3) & 7)) * 8;   // u16
  const u16* gA = A + (m0 + (tid >> 3)) * K + colsw;
  const u16* gB = Bm + (n0 + (tid >> 3)) * K + colsw;

  for (long kt = 0; kt < K; kt += 64) {
    __syncthreads();
    #pragma unroll
    for (int r = 0; r < 4; ++r) {
      gload_lds16(gA + (size_t)(r * 32) * K + kt, &Al[r * 2048 + tid * 8]);
      gload_lds16(gB + (size_t)(r * 32) * K + kt, &Bl[r * 2048 + tid * 8]);
    }
    __syncthreads();
    #pragma unroll
    for (int ks = 0; ks < 2; ++ks) {
      const int slot = ((ks * 4 + g) ^ L7) * 8;
      bf16x8 av[4], bv[4];
      #pragma unroll
      for (int i = 0; i < 4; ++i) {
        av[i] = __builtin_bit_cast(bf16x8, *reinterpret_cast<const us8*>(
            &Al[(wr * 64 + i * 16 + L15) * 64 + slot]));
        bv[i] = __builtin_bit_cast(bf16x8, *reinterpret_cast<const us8*>(
            &Bl[(wc * 64 + i * 16 + L15) * 64 + slot]));
      }
      #pragma unroll
      for (int i = 0; i < 4; ++i)
        #pragma unroll
        for (int j = 0; j < 4; ++j)
          acc[i][j] = __builtin_amdgcn_mfma_f32_16x16x32_bf16(av[i], bv[j], acc[i][j], 0, 0, 0);
    }
  }

  #pragma unroll
  for (int i = 0; i < 4; ++i) {
    #pragma unroll
    for (int q = 0; q < 4; ++q) {
      long row = m0 + wr * 64 + i * 16 + g * 4 + q;
      float inv;
      if (EP == 3) inv = 1.0f / rowsum[row];
      #pragma unroll
      for (int j = 0; j < 4; ++j) {
        long col = n0 + wc * 64 + j * 16 + L15;
        float v = acc[i][j][q];
        if (EP == 1) Cb[row * N + col] = f2bf(v + bias[col]);
        else         Cf[row * N + col] = v * inv;
      }
    }
  }
  (void)scale;
}

extern "C" void kernel_launch(void* const* d_in, const int* in_sizes, int n_in,
                              void* d_out, int out_size, void* d_ws, size_t ws_size,
                              hipStream_t stream) {
  (void)in_sizes; (void)n_in; (void)out_size;
  const float* y     = (const float*)d_in[0];
  const float* Wy_w  = (const float*)d_in[1];
  const float* Wy_b  = (const float*)d_in[2];
  const float* Wz_w  = (const float*)d_in[3];
  const float* Wz_b  = (const float*)d_in[4];
  const float* dic   = (const float*)d_in[5];
  const float* prior = (const float*)d_in[6];
  float* out = (float*)d_out;

  // allow 128 KiB dynamic LDS (unconditional, idempotent, capture-safe)
  hipFuncSetAttribute(reinterpret_cast<const void*>(&k_gemm8<0>),
                      hipFuncAttributeMaxDynamicSharedMemorySize, 131072);
  hipFuncSetAttribute(reinterpret_cast<const void*>(&k_gemm8<1>),
                      hipFuncAttributeMaxDynamicSharedMemorySize, 131072);

  char* base = (char*)d_ws;
  size_t off = 0;
  auto alloc = [&](size_t bytes) -> char* {
    char* p = base + off;
    off = (off + bytes + 255) & ~(size_t)255;
    return p;
  };
  u16*  Yb   = (u16*)alloc((size_t)M_ * D_ * 2);
  u16*  Db   = (u16*)alloc((size_t)N_ * D_ * 2);
  u16*  Wyb  = (u16*)alloc((size_t)D_ * D_ * 2);
  u16*  Wzb  = (u16*)alloc((size_t)D_ * D_ * 2);
  u16*  Qb   = (u16*)alloc((size_t)M_ * D_ * 2);
  u16*  Kb   = (u16*)alloc((size_t)N_ * D_ * 2);
  u16*  Vt   = (u16*)alloc((size_t)D_ * N_ * 2);
  float* rowsum = (float*)alloc((size_t)M_ * 4);
  size_t fixed = off;
  // chunk M so S-chunk (bf16) + 2 split-K partials (f32) fit in ws
  int Mc = M_;
  while (Mc > 256 &&
         fixed + (size_t)Mc * N_ * 2 + 2 * (size_t)Mc * D_ * 4 > ws_size)
    Mc >>= 1;
  u16*   Sc   = (u16*)alloc((size_t)Mc * N_ * 2);
  float* part = (float*)alloc(2 * (size_t)Mc * D_ * 4);
  const long partStride = (long)Mc * D_;

  // zero row-sum accumulators (stream-ordered, capture-safe)
  hipMemsetAsync(rowsum, 0, (size_t)M_ * 4, stream);

  auto cvt = [&](const float* src, u16* dst, size_t n) {
    int n4 = (int)(n / 4);
    int blocks = (n4 + 255) / 256;
    if (blocks > 2048) blocks = 2048;
    hipLaunchKernelGGL(k_cvt_bf16, dim3(blocks), dim3(256), 0, stream, src, dst, n4);
  };
  cvt(y,    Yb,  (size_t)M_ * D_);
  cvt(Wy_w, Wyb, (size_t)D_ * D_);
  cvt(Wz_w, Wzb, (size_t)D_ * D_);

  // fused: Db = bf16(dic), Vt = bf16(prior*dic^T)
  hipLaunchKernelGGL(k_build_vt, dim3(N_ / 32, D_ / 32), dim3(32, 8), 0, stream,
                     dic, prior, Db, Vt);

  // Q = Yb * Wyb^T + by ; K = Db * Wzb^T + bz   (bf16 out, swizzled kernel)
  hipLaunchKernelGGL(HIP_KERNEL_NAME(k_gemm_nt<1>), dim3(D_ / 128, M_ / 128), dim3(256), 0, stream,
                     Yb, Wyb, (float*)nullptr, Qb, Wy_b, (const float*)nullptr, 0.f, D_, (long)D_);
  hipLaunchKernelGGL(HIP_KERNEL_NAME(k_gemm_nt<1>), dim3(D_ / 128, N_ / 128), dim3(256), 0, stream,
                     Db, Wzb, (float*)nullptr, Kb, Wz_b, (const float*)nullptr, 0.f, D_, (long)D_);

  const float scale = 0.036084391824351615f;  // 1/sqrt(768)
  for (int mc = 0; mc < M_; mc += Mc) {
    // P~ = exp(Q*K^T * scale) (bf16) + row-sums, fused into the S GEMM
    {
      const int nbx = N_ / 256, nby = Mc / 256;
      hipLaunchKernelGGL(HIP_KERNEL_NAME(k_gemm8<0>), dim3(nbx * nby), dim3(512), 131072, stream,
                         Qb + (size_t)mc * D_, Kb, Sc, rowsum + mc, scale,
                         (long)D_, D_, N_, nbx, nbx * nby, 0L);
    }
    // PV partials: part[s] = P~ * Vt^T over k-range s  (split-K = 2)
    {
      const int nbx = D_ / 256, nby = Mc / 256, tps = nbx * nby;
      hipLaunchKernelGGL(HIP_KERNEL_NAME(k_gemm8<1>), dim3(tps * 2), dim3(512), 131072, stream,
                         Sc, Vt, (u16*)nullptr, part, 1.0f,
                         (long)N_, N_ / 2, D_, nbx, tps, partStride);
    }
    // out = (part0 + part1) / rowsum
    {
      int n4 = Mc * D_ / 4;
      int blocks = (n4 + 255) / 256;
      if (blocks > 2048) blocks = 2048;
      hipLaunchKernelGGL(k_reduce2, dim3(blocks), dim3(256), 0, stream,
                         part, partStride, rowsum + mc, out + (size_t)mc * D_, n4);
    }
  }
}

// Round 14
// 295.750 us; speedup vs baseline: 1.1103x; 1.0082x over previous
//
#include <hip/hip_runtime.h>
#include <stdint.h>

#define M_ 8192   // B*L
#define D_ 768
#define N_ 8192

typedef unsigned short u16;
typedef __attribute__((ext_vector_type(8))) unsigned short us8;
typedef __attribute__((ext_vector_type(8))) __bf16 bf16x8;
typedef __attribute__((ext_vector_type(4))) float f32x4;

__device__ __forceinline__ u16 f2bf(float f) {
  uint32_t u = __builtin_bit_cast(uint32_t, f);
  u += 0x7FFFu + ((u >> 16) & 1u);   // RNE
  return (u16)(u >> 16);
}

__device__ __forceinline__ void gload_lds16(const void* g, void* l) {
  __builtin_amdgcn_global_load_lds(
      (__attribute__((address_space(1))) void*)g,
      (__attribute__((address_space(3))) void*)l, 16, 0, 0);
}

// ---------------- f32 -> bf16 convert (vectorized) ----------------
__global__ __launch_bounds__(256)
void k_cvt_bf16(const float* __restrict__ in, u16* __restrict__ out, int n4) {
  int stride = gridDim.x * blockDim.x;
  for (int i = blockIdx.x * blockDim.x + threadIdx.x; i < n4; i += stride) {
    float4 v = reinterpret_cast<const float4*>(in)[i];
    ushort4 o;
    o.x = f2bf(v.x); o.y = f2bf(v.y); o.z = f2bf(v.z); o.w = f2bf(v.w);
    reinterpret_cast<ushort4*>(out)[i] = o;
  }
}

// ------------- two-array f32 -> bf16 convert (both weights) -------------
__global__ __launch_bounds__(256)
void k_cvt2(const float* __restrict__ a, const float* __restrict__ b,
            u16* __restrict__ da, u16* __restrict__ db, int n4each) {
  int stride = gridDim.x * blockDim.x;
  for (int i = blockIdx.x * blockDim.x + threadIdx.x; i < 2 * n4each; i += stride) {
    const float* s = (i < n4each) ? a : b;
    u16* d = (i < n4each) ? da : db;
    int j = (i < n4each) ? i : i - n4each;
    float4 v = reinterpret_cast<const float4*>(s)[j];
    ushort4 o;
    o.x = f2bf(v.x); o.y = f2bf(v.y); o.z = f2bf(v.z); o.w = f2bf(v.w);
    reinterpret_cast<ushort4*>(d)[j] = o;
  }
}

// ---- fused: Db[n][d] = bf16(dic[n][d]);  Vt[d][n] = bf16(prior[n]*dic[n][d])
__global__ __launch_bounds__(256)
void k_build_vt(const float* __restrict__ dic, const float* __restrict__ prior,
                u16* __restrict__ Db, u16* __restrict__ Vt) {
  __shared__ float t[32][33];
  const int n0 = blockIdx.x * 32, d0 = blockIdx.y * 32;
  const int tx = threadIdx.x, ty = threadIdx.y;
  #pragma unroll
  for (int i = ty; i < 32; i += 8) {
    float v = dic[(size_t)(n0 + i) * D_ + d0 + tx];
    Db[(size_t)(n0 + i) * D_ + d0 + tx] = f2bf(v);
    t[i][tx] = v * prior[n0 + i];
  }
  __syncthreads();
  #pragma unroll
  for (int i = ty; i < 32; i += 8)
    Vt[(size_t)(d0 + i) * N_ + n0 + tx] = f2bf(t[tx][i]);
}

// ============ 256x256 NT bf16 GEMM — round-7 schedule (S path) ======
// Cb = bf16(exp(acc*scale)), row-sums via LDS scratch -> 1 atomic/row/block.
template<int EP>
__global__ __launch_bounds__(512, 2)
void k_gemm8(const u16* __restrict__ A, const u16* __restrict__ Bm,
             u16* __restrict__ Cb, float* __restrict__ Cf, float scale,
             long ldk, int K, int Ncols, int nbx, int tps, long partStride) {
  extern __shared__ u16 ldsu[];   // 65536 u16 = 128 KiB: [buf2][mat2][16384]
  const int tid = threadIdx.x;
  const int lane = tid & 63, wid = tid >> 6;
  const int wr = wid >> 2, wc = wid & 3;
  const int L15 = lane & 15, L7 = lane & 7, g = lane >> 4;

  const int nwg = gridDim.x;
  const int bid = blockIdx.x;
  const int wg = ((nwg & 7) == 0) ? ((bid & 7) * (nwg >> 3) + (bid >> 3)) : bid;
  const int s = wg / tps;
  const int r = wg % tps;
  const int bx = r % nbx, by = r / nbx;
  const long m0 = (long)by * 256;
  const long n0 = (long)bx * 256;
  const int NT = K >> 6;

  int aBase[2], bBase[2];
  #pragma unroll
  for (int ks = 0; ks < 2; ++ks) {
    const int slot = (((ks * 4 + g) ^ L7) << 3);
    aBase[ks] = wr * 8192 + L15 * 64 + slot;
    bBase[ks] = 16384 + (wc >> 1) * 8192 + (wc & 1) * 4096 + L15 * 64 + slot;
  }

  const int rowoff = wid * 8 + (lane >> 3);
  const int colsw = ((lane & 7) ^ (lane >> 3)) << 3;   // u16
  const u16* Ag = A + m0 * ldk + (long)s * K;
  const u16* Bg = Bm + n0 * ldk + (long)s * K;
  u16* ldsW = ldsu + tid * 8;

  auto g1 = [&](int t, int mat, int r0) {
    if (t >= NT) return;
    const u16* src = (mat ? Bg : Ag) + (size_t)(r0 + rowoff) * ldk
                     + (size_t)t * 64 + colsw;
    gload_lds16(src, ldsW + (t & 1) * 32768 + mat * 16384 + (r0 >> 6) * 512 * 8);
  };

#define RD_B()                                                              \
  _Pragma("unroll") for (int j = 0; j < 4; ++j)                             \
    _Pragma("unroll") for (int ks = 0; ks < 2; ++ks)                        \
      bfr[j][ks] = __builtin_bit_cast(bf16x8,                               \
          *reinterpret_cast<const us8*>(&ldsu[bufOff + bBase[ks] + j * 1024]));
#define RD_A(q)                                                             \
  _Pragma("unroll") for (int t = 0; t < 2; ++t)                             \
    _Pragma("unroll") for (int ks = 0; ks < 2; ++ks)                        \
      afr[t][ks] = __builtin_bit_cast(bf16x8,                               \
          *reinterpret_cast<const us8*>(                                    \
              &ldsu[bufOff + aBase[ks] + (2 * (q) + t) * 1024]));
#define LGKM0()                                                             \
  asm volatile("s_waitcnt lgkmcnt(0)" ::: "memory");                        \
  __builtin_amdgcn_sched_barrier(0);
#define MM(p)                                                               \
  __builtin_amdgcn_s_setprio(1);                                            \
  _Pragma("unroll") for (int t = 0; t < 2; ++t)                             \
    _Pragma("unroll") for (int j = 0; j < 4; ++j)                           \
      _Pragma("unroll") for (int ks = 0; ks < 2; ++ks)                      \
        acc[2 * (p) + t][j] = __builtin_amdgcn_mfma_f32_16x16x32_bf16(      \
            afr[t][ks], bfr[j][ks], acc[2 * (p) + t][j], 0, 0, 0);          \
  __builtin_amdgcn_s_setprio(0);

  g1(0, 1, 0); g1(0, 1, 64); g1(0, 1, 128); g1(0, 1, 192);
  g1(0, 0, 0); g1(0, 0, 128); g1(0, 0, 64); g1(0, 0, 192);
  g1(1, 1, 0); g1(1, 1, 64);
  g1(1, 1, 128); g1(1, 1, 192);
  g1(1, 0, 0); g1(1, 0, 128);
  asm volatile("s_waitcnt vmcnt(6)" ::: "memory");
  __builtin_amdgcn_s_barrier();

  f32x4 acc[8][4] = {};

  for (int k = 0; k < NT; ++k) {
    const int bufOff = (k & 1) * 32768;
    bf16x8 bfr[4][2];

    { bf16x8 afr[2][2];
      g1(k + 1, 0, 64); g1(k + 1, 0, 192);
      RD_B(); RD_A(0);
      asm volatile("s_waitcnt lgkmcnt(8)" ::: "memory");
      __builtin_amdgcn_s_barrier();
      LGKM0(); MM(0);
    }
    { bf16x8 afr[2][2];
      RD_A(1);
      g1(k + 2, 1, 0); g1(k + 2, 1, 64);
      __builtin_amdgcn_s_barrier();
      LGKM0(); MM(1);
    }
    { bf16x8 afr[2][2];
      RD_A(2);
      g1(k + 2, 1, 128); g1(k + 2, 1, 192);
      __builtin_amdgcn_s_barrier();
      LGKM0(); MM(2);
    }
    { bf16x8 afr[2][2];
      RD_A(3);
      g1(k + 2, 0, 0); g1(k + 2, 0, 128);
      if (k < NT - 2) asm volatile("s_waitcnt vmcnt(6)" ::: "memory");
      else            asm volatile("s_waitcnt vmcnt(0)" ::: "memory");
      __builtin_amdgcn_s_barrier();
      LGKM0(); MM(3);
    }
  }
#undef RD_B
#undef RD_A
#undef LGKM0
#undef MM

  if (EP == 0) {
    __builtin_amdgcn_s_barrier();
    float* lsum = reinterpret_cast<float*>(ldsu);   // [256][68] f32, padded
    #pragma unroll
    for (int i = 0; i < 8; ++i) {
      #pragma unroll
      for (int q = 0; q < 4; ++q) {
        const int rl = wr * 128 + i * 16 + g * 4 + q;
        const long row = m0 + rl;
        float rsum = 0.f;
        #pragma unroll
        for (int j = 0; j < 4; ++j) {
          float v = __expf(acc[i][j][q] * scale);
          rsum += v;
          Cb[row * (long)Ncols + n0 + wc * 64 + j * 16 + L15] = f2bf(v);
        }
        lsum[rl * 68 + wc * 16 + L15] = rsum;
      }
    }
    __builtin_amdgcn_s_barrier();
    {
      const int rl = tid >> 1, half = tid & 1;
      const float4* rp =
          reinterpret_cast<const float4*>(&lsum[rl * 68 + half * 32]);
      float s4 = 0.f;
      #pragma unroll
      for (int c = 0; c < 8; ++c) {
        float4 v = rp[c];
        s4 += (v.x + v.y) + (v.z + v.w);
      }
      s4 += __shfl_xor(s4, 1);
      if (half == 0) atomicAdd(&Cf[m0 + rl], s4);
    }
  } else {
    #pragma unroll
    for (int i = 0; i < 8; ++i)
      #pragma unroll
      for (int j = 0; j < 4; ++j)
        #pragma unroll
        for (int q = 0; q < 4; ++q) {
          long row = m0 + wr * 128 + i * 16 + g * 4 + q;
          long col = n0 + wc * 64 + j * 16 + L15;
          Cf[(long)s * partStride + row * (long)Ncols + col] = acc[i][j][q];
        }
  }
}

// ====== 128x128 NT bf16 GEMM — round-7 phases, 64 KiB LDS, 2 blocks/CU ====
// PV: out[row*D_+col] = acc / rowsum[row].  4 waves (2Mx2N), per-wave 64x64.
// Per phase: {2 A-frag reads (ph0 also 8 B) ; 2 gloads ; barrier ; lgkm0 ;
// 8 MFMA}. vmcnt(6) at ph3 retires through ph0's A-hi(k+1) -> tile k+1
// resident (identical chain to the proven 256^2 schedule).
__global__ __launch_bounds__(256, 2)
void k_pv128(const u16* __restrict__ A, const u16* __restrict__ Bm,
             const float* __restrict__ rowsum, float* __restrict__ out,
             int nbx, long ldk, int K) {
  extern __shared__ u16 ldsu[];   // 32768 u16 = 64 KiB: [buf2][mat2][8192]
  const int tid = threadIdx.x;
  const int lane = tid & 63, wid = tid >> 6;
  const int wr = wid >> 1, wc = wid & 1;
  const int L15 = lane & 15, L7 = lane & 7, g = lane >> 4;

  const int nwg = gridDim.x, bid = blockIdx.x;
  const int wg = ((nwg & 7) == 0) ? ((bid & 7) * (nwg >> 3) + (bid >> 3)) : bid;
  const int bx = wg % nbx, by = wg / nbx;
  const long m0 = (long)by * 128, n0 = (long)bx * 128;
  const int NT = K >> 6;

  int aBase[2], bBase[2];
  #pragma unroll
  for (int ks = 0; ks < 2; ++ks) {
    const int slot = (((ks * 4 + g) ^ L7) << 3);
    aBase[ks] = (wr * 64 + L15) * 64 + slot;          // + i*1024
    bBase[ks] = 8192 + (wc * 64 + L15) * 64 + slot;   // + j*1024
  }

  const int rowoff = tid >> 3;                          // 0..31
  const int colsw = ((tid & 7) ^ ((tid >> 3) & 7)) << 3;
  const u16* Ag = A + m0 * ldk;
  const u16* Bg = Bm + n0 * ldk;
  u16* ldsW = ldsu + tid * 8;

  // stage 32 rows: tile t, matrix mat, base row r0 in {0,32,64,96}
  auto g1 = [&](int t, int mat, int r0) {
    if (t >= NT) return;
    const u16* src = (mat ? Bg : Ag) + (size_t)(r0 + rowoff) * ldk
                     + (size_t)t * 64 + colsw;
    gload_lds16(src, ldsW + (t & 1) * 16384 + mat * 8192 + r0 * 64);
  };

#define PLGKM0()                                                            \
  asm volatile("s_waitcnt lgkmcnt(0)" ::: "memory");                        \
  __builtin_amdgcn_sched_barrier(0);
#define PMM(p)                                                              \
  __builtin_amdgcn_s_setprio(1);                                            \
  _Pragma("unroll") for (int j = 0; j < 4; ++j)                             \
    _Pragma("unroll") for (int ks = 0; ks < 2; ++ks)                        \
      acc[p][j] = __builtin_amdgcn_mfma_f32_16x16x32_bf16(                  \
          afr[ks], bfr[j][ks], acc[p][j], 0, 0, 0);                         \
  __builtin_amdgcn_s_setprio(0);
#define PRD_A(q)                                                            \
  _Pragma("unroll") for (int ks = 0; ks < 2; ++ks)                          \
    afr[ks] = __builtin_bit_cast(bf16x8,                                    \
        *reinterpret_cast<const us8*>(&ldsu[bufOff + aBase[ks] + (q) * 1024]));

  // prologue: tile0 full (8 gloads) + tile1 {B, A-lo} (6); tile0 resident
  g1(0, 1, 0); g1(0, 1, 32); g1(0, 1, 64); g1(0, 1, 96);
  g1(0, 0, 0); g1(0, 0, 32); g1(0, 0, 64); g1(0, 0, 96);
  g1(1, 1, 0); g1(1, 1, 32); g1(1, 1, 64); g1(1, 1, 96);
  g1(1, 0, 0); g1(1, 0, 32);
  asm volatile("s_waitcnt vmcnt(6)" ::: "memory");
  __builtin_amdgcn_s_barrier();

  f32x4 acc[4][4] = {};

  for (int k = 0; k < NT; ++k) {
    const int bufOff = (k & 1) * 16384;
    bf16x8 bfr[4][2];

    { // ph0: read B(8)+A0(2); stage A-hi(k+1)
      bf16x8 afr[2];
      g1(k + 1, 0, 64); g1(k + 1, 0, 96);
      #pragma unroll
      for (int j = 0; j < 4; ++j)
        #pragma unroll
        for (int ks = 0; ks < 2; ++ks)
          bfr[j][ks] = __builtin_bit_cast(bf16x8,
              *reinterpret_cast<const us8*>(&ldsu[bufOff + bBase[ks] + j * 1024]));
      PRD_A(0);
      asm volatile("s_waitcnt lgkmcnt(8)" ::: "memory");
      __builtin_amdgcn_s_barrier();
      PLGKM0(); PMM(0);
    }
    { // ph1: read A1; stage B-h0(k+2)
      bf16x8 afr[2];
      PRD_A(1);
      g1(k + 2, 1, 0); g1(k + 2, 1, 32);
      __builtin_amdgcn_s_barrier();
      PLGKM0(); PMM(1);
    }
    { // ph2: read A2; stage B-h1(k+2)
      bf16x8 afr[2];
      PRD_A(2);
      g1(k + 2, 1, 64); g1(k + 2, 1, 96);
      __builtin_amdgcn_s_barrier();
      PLGKM0(); PMM(2);
    }
    { // ph3: read A3; stage A-lo(k+2); counted vmcnt
      bf16x8 afr[2];
      PRD_A(3);
      g1(k + 2, 0, 0); g1(k + 2, 0, 32);
      if (k < NT - 2) asm volatile("s_waitcnt vmcnt(6)" ::: "memory");
      else            asm volatile("s_waitcnt vmcnt(0)" ::: "memory");
      __builtin_amdgcn_s_barrier();
      PLGKM0(); PMM(3);
    }
  }
#undef PLGKM0
#undef PMM
#undef PRD_A

  // epilogue: out = acc / rowsum[row]
  #pragma unroll
  for (int i = 0; i < 4; ++i) {
    #pragma unroll
    for (int q = 0; q < 4; ++q) {
      long row = m0 + wr * 64 + i * 16 + g * 4 + q;
      float inv = 1.0f / rowsum[row];
      #pragma unroll
      for (int j = 0; j < 4; ++j) {
        long col = n0 + wc * 64 + j * 16 + L15;
        out[row * D_ + col] = acc[i][j][q] * inv;
      }
    }
  }
}

// ---------- 128x128 NT bf16 GEMM, T2-swizzled (projections) ----------
template<int EP>
__global__ __launch_bounds__(256, 2)
void k_gemm_nt(const u16* __restrict__ A, const u16* __restrict__ Bm,
               float* __restrict__ Cf, u16* __restrict__ Cb,
               const float* __restrict__ bias, const float* __restrict__ rowsum,
               float scale, int N, long K) {
  __shared__ u16 Al[128 * 64];
  __shared__ u16 Bl[128 * 64];
  const int tid = threadIdx.x;
  const int lane = tid & 63;
  const int wave = tid >> 6;
  const int wr = wave >> 1, wc = wave & 1;
  const int L15 = lane & 15, L7 = lane & 7, g = lane >> 4;
  const long m0 = (long)blockIdx.y * 128;
  const long n0 = (long)blockIdx.x * 128;

  f32x4 acc[4][4] = {};

  const int colsw = ((tid & 7) ^ ((tid >> 3) & 7)) * 8;   // u16
  const u16* gA = A + (m0 + (tid >> 3)) * K + colsw;
  const u16* gB = Bm + (n0 + (tid >> 3)) * K + colsw;

  for (long kt = 0; kt < K; kt += 64) {
    __syncthreads();
    #pragma unroll
    for (int r = 0; r < 4; ++r) {
      gload_lds16(gA + (size_t)(r * 32) * K + kt, &Al[r * 2048 + tid * 8]);
      gload_lds16(gB + (size_t)(r * 32) * K + kt, &Bl[r * 2048 + tid * 8]);
    }
    __syncthreads();
    #pragma unroll
    for (int ks = 0; ks < 2; ++ks) {
      const int slot = ((ks * 4 + g) ^ L7) * 8;
      bf16x8 av[4], bv[4];
      #pragma unroll
      for (int i = 0; i < 4; ++i) {
        av[i] = __builtin_bit_cast(bf16x8, *reinterpret_cast<const us8*>(
            &Al[(wr * 64 + i * 16 + L15) * 64 + slot]));
        bv[i] = __builtin_bit_cast(bf16x8, *reinterpret_cast<const us8*>(
            &Bl[(wc * 64 + i * 16 + L15) * 64 + slot]));
      }
      #pragma unroll
      for (int i = 0; i < 4; ++i)
        #pragma unroll
        for (int j = 0; j < 4; ++j)
          acc[i][j] = __builtin_amdgcn_mfma_f32_16x16x32_bf16(av[i], bv[j], acc[i][j], 0, 0, 0);
    }
  }

  #pragma unroll
  for (int i = 0; i < 4; ++i) {
    #pragma unroll
    for (int q = 0; q < 4; ++q) {
      long row = m0 + wr * 64 + i * 16 + g * 4 + q;
      float inv;
      if (EP == 3) inv = 1.0f / rowsum[row];
      #pragma unroll
      for (int j = 0; j < 4; ++j) {
        long col = n0 + wc * 64 + j * 16 + L15;
        float v = acc[i][j][q];
        if (EP == 1) Cb[row * N + col] = f2bf(v + bias[col]);
        else         Cf[row * N + col] = v * inv;
      }
    }
  }
  (void)scale;
}

extern "C" void kernel_launch(void* const* d_in, const int* in_sizes, int n_in,
                              void* d_out, int out_size, void* d_ws, size_t ws_size,
                              hipStream_t stream) {
  (void)in_sizes; (void)n_in; (void)out_size;
  const float* y     = (const float*)d_in[0];
  const float* Wy_w  = (const float*)d_in[1];
  const float* Wy_b  = (const float*)d_in[2];
  const float* Wz_w  = (const float*)d_in[3];
  const float* Wz_b  = (const float*)d_in[4];
  const float* dic   = (const float*)d_in[5];
  const float* prior = (const float*)d_in[6];
  float* out = (float*)d_out;

  hipFuncSetAttribute(reinterpret_cast<const void*>(&k_gemm8<0>),
                      hipFuncAttributeMaxDynamicSharedMemorySize, 131072);
  hipFuncSetAttribute(reinterpret_cast<const void*>(&k_pv128),
                      hipFuncAttributeMaxDynamicSharedMemorySize, 65536);

  char* base = (char*)d_ws;
  size_t off = 0;
  auto alloc = [&](size_t bytes) -> char* {
    char* p = base + off;
    off = (off + bytes + 255) & ~(size_t)255;
    return p;
  };
  u16*  Yb   = (u16*)alloc((size_t)M_ * D_ * 2);
  u16*  Db   = (u16*)alloc((size_t)N_ * D_ * 2);
  u16*  Wyb  = (u16*)alloc((size_t)D_ * D_ * 2);
  u16*  Wzb  = (u16*)alloc((size_t)D_ * D_ * 2);
  u16*  Qb   = (u16*)alloc((size_t)M_ * D_ * 2);
  u16*  Kb   = (u16*)alloc((size_t)N_ * D_ * 2);
  u16*  Vt   = (u16*)alloc((size_t)D_ * N_ * 2);
  float* rowsum = (float*)alloc((size_t)M_ * 4);
  size_t fixed = off;
  int Mc = M_;
  while (Mc > 256 && fixed + (size_t)Mc * N_ * 2 > ws_size) Mc >>= 1;
  u16* Sc = (u16*)alloc((size_t)Mc * N_ * 2);

  // zero row-sum accumulators (stream-ordered, capture-safe)
  hipMemsetAsync(rowsum, 0, (size_t)M_ * 4, stream);

  // y -> bf16
  {
    int n4 = M_ * D_ / 4;
    int blocks = (n4 + 255) / 256;
    if (blocks > 2048) blocks = 2048;
    hipLaunchKernelGGL(k_cvt_bf16, dim3(blocks), dim3(256), 0, stream, y, Yb, n4);
  }
  // both weights -> bf16 in one launch
  {
    int n4e = D_ * D_ / 4;
    int blocks = (2 * n4e + 255) / 256;
    if (blocks > 2048) blocks = 2048;
    hipLaunchKernelGGL(k_cvt2, dim3(blocks), dim3(256), 0, stream,
                       Wy_w, Wz_w, Wyb, Wzb, n4e);
  }

  // fused: Db = bf16(dic), Vt = bf16(prior*dic^T)
  hipLaunchKernelGGL(k_build_vt, dim3(N_ / 32, D_ / 32), dim3(32, 8), 0, stream,
                     dic, prior, Db, Vt);

  // Q = Yb * Wyb^T + by ; K = Db * Wzb^T + bz   (bf16 out, swizzled kernel)
  hipLaunchKernelGGL(HIP_KERNEL_NAME(k_gemm_nt<1>), dim3(D_ / 128, M_ / 128), dim3(256), 0, stream,
                     Yb, Wyb, (float*)nullptr, Qb, Wy_b, (const float*)nullptr, 0.f, D_, (long)D_);
  hipLaunchKernelGGL(HIP_KERNEL_NAME(k_gemm_nt<1>), dim3(D_ / 128, N_ / 128), dim3(256), 0, stream,
                     Db, Wzb, (float*)nullptr, Kb, Wz_b, (const float*)nullptr, 0.f, D_, (long)D_);

  const float scale = 0.036084391824351615f;  // 1/sqrt(768)
  for (int mc = 0; mc < M_; mc += Mc) {
    // P~ = exp(Q*K^T * scale) (bf16) + row-sums, fused into the S GEMM
    {
      const int nbx = N_ / 256, nby = Mc / 256;
      hipLaunchKernelGGL(HIP_KERNEL_NAME(k_gemm8<0>), dim3(nbx * nby), dim3(512), 131072, stream,
                         Qb + (size_t)mc * D_, Kb, Sc, rowsum + mc, scale,
                         (long)D_, D_, N_, nbx, nbx * nby, 0L);
    }
    // out = (P~ * Vt^T) / rowsum — phased 128^2, 2 blocks/CU, full fill
    {
      const int nbx = D_ / 128, nby = Mc / 128;   // 6 x 64 = 384 blocks
      hipLaunchKernelGGL(k_pv128, dim3(nbx * nby), dim3(256), 65536, stream,
                         Sc, Vt, rowsum + mc, out + (size_t)mc * D_,
                         nbx, (long)N_, N_);
    }
  }
}